// Round 1
// baseline (34103.644 us; speedup 1.0000x reference)
//
#include <hip/hip_runtime.h>
#include <cstddef>

// Problem constants
#define S_LEN 64
#define BATCH 128
#define T_LEN 32
#define E_DIM 256
#define HE_DIM 512
#define HD_DIM 512
#define VOCAB 32000
#define XDIM 1792   // HD + 2*HE + E

__device__ __forceinline__ float sigm(float x) { return 1.0f / (1.0f + expf(-x)); }

// ---------------------------------------------------------------- utilities
__global__ void zero_kernel(float* __restrict__ p, int n) {
    int i = blockIdx.x * 256 + threadIdx.x;
    if (i < n) p[i] = 0.f;
}

// out[row][k] = table[idx[row]*E + k]
__global__ void gather_emb(const float* __restrict__ table, const int* __restrict__ idx,
                           float* __restrict__ out, int total) {
    int i = blockIdx.x * 256 + threadIdx.x;
    if (i >= total) return;
    int row = i >> 8;          // / E_DIM
    int k   = i & 255;
    out[i] = table[(size_t)idx[row] * E_DIM + k];
}

// X[(t*B+b)][1536 + k] = emb_dec[trg[t*B+b]*E + k], t in [0, T-1)
__global__ void gather_trg(const float* __restrict__ table, const int* __restrict__ trg,
                           float* __restrict__ X, int total) {
    int i = blockIdx.x * 256 + threadIdx.x;
    if (i >= total) return;
    int row = i >> 8;
    int k   = i & 255;
    X[(size_t)row * XDIM + 1536 + k] = table[(size_t)trg[row] * E_DIM + k];
}

// -------------------------------------------------- encoder GRU step (both dirs)
// grid (8 j-tiles, 8 b-tiles, 2 dirs), block (64,16)
__global__ __launch_bounds__(1024) void gru_enc_step(
    const float* __restrict__ emb,      // [S][B][E]
    const float* __restrict__ h_in,     // [B][1024]  fwd 0:512, bwd 512:1024
    float* __restrict__ h_out,          // [B][1024]
    float* __restrict__ enc_bt,         // [B][S][1024]
    const float* __restrict__ Wih_f, const float* __restrict__ Whh_f,
    const float* __restrict__ bih_f, const float* __restrict__ bhh_f,
    const float* __restrict__ Wih_b, const float* __restrict__ Whh_b,
    const float* __restrict__ bih_b, const float* __restrict__ bhh_b,
    int s)
{
    __shared__ float xs[16][E_DIM];
    __shared__ float hs[16][HE_DIM];
    const int dir = blockIdx.z;
    const int p   = dir ? (S_LEN - 1 - s) : s;
    const float* Wih = dir ? Wih_b : Wih_f;
    const float* Whh = dir ? Whh_b : Whh_f;
    const float* bih = dir ? bih_b : bih_f;
    const float* bhh = dir ? bhh_b : bhh_f;
    const int tx = threadIdx.x, ty = threadIdx.y;
    const int tid = ty * 64 + tx;
    const int b0  = blockIdx.y * 16;
    for (int i = tid; i < 16 * E_DIM; i += 1024)
        xs[i >> 8][i & 255] = emb[((size_t)p * BATCH + b0 + (i >> 8)) * E_DIM + (i & 255)];
    for (int i = tid; i < 16 * HE_DIM; i += 1024)
        hs[i >> 9][i & 511] = h_in[(size_t)(b0 + (i >> 9)) * 1024 + dir * HE_DIM + (i & 511)];
    __syncthreads();
    const int j = blockIdx.x * 64 + tx;
    float g_i[3], g_h[3];
#pragma unroll
    for (int g = 0; g < 3; ++g) {
        const int row = g * HE_DIM + j;
        const float4* wi = (const float4*)(Wih + (size_t)row * E_DIM);
        const float4* xv = (const float4*)xs[ty];
        float acc = bih[row];
#pragma unroll 4
        for (int k = 0; k < E_DIM / 4; ++k) {
            float4 w = wi[k], x = xv[k];
            acc += w.x * x.x + w.y * x.y + w.z * x.z + w.w * x.w;
        }
        g_i[g] = acc;
        const float4* wh = (const float4*)(Whh + (size_t)row * HE_DIM);
        const float4* hv = (const float4*)hs[ty];
        acc = bhh[row];
#pragma unroll 4
        for (int k = 0; k < HE_DIM / 4; ++k) {
            float4 w = wh[k], h = hv[k];
            acc += w.x * h.x + w.y * h.y + w.z * h.z + w.w * h.w;
        }
        g_h[g] = acc;
    }
    float r = sigm(g_i[0] + g_h[0]);
    float z = sigm(g_i[1] + g_h[1]);
    float n = tanhf(g_i[2] + r * g_h[2]);
    float h2 = (1.f - z) * n + z * hs[ty][j];
    const int b = b0 + ty;
    h_out[(size_t)b * 1024 + dir * HE_DIM + j] = h2;
    enc_bt[((size_t)b * S_LEN + p) * 1024 + dir * HE_DIM + j] = h2;
}

// -------------------------------------------------- batched matvec (M=128 GEMMs)
// out[b][n] = act(dot(A[b,:K], W[n,:K]) + bias[n]); grid (N/256, B), block 256
__global__ __launch_bounds__(256) void matvec_b(
    const float* __restrict__ A, int lda,
    const float* __restrict__ W, int ldw,
    float* __restrict__ out, int ldo,
    int K, const float* __restrict__ bias, int act)
{
    __shared__ float as[1024];
    const int b = blockIdx.y, tid = threadIdx.x;
    for (int i = tid; i < K; i += 256) as[i] = A[(size_t)b * lda + i];
    __syncthreads();
    const int n = blockIdx.x * 256 + tid;
    const float4* w4 = (const float4*)(W + (size_t)n * ldw);
    const float4* a4 = (const float4*)as;
    float acc = bias ? bias[n] : 0.f;
#pragma unroll 4
    for (int k = 0; k < K / 4; ++k) {
        float4 w = w4[k], a = a4[k];
        acc += w.x * a.x + w.y * a.y + w.z * a.z + w.w * a.w;
    }
    if (act) acc = tanhf(acc);
    out[(size_t)b * ldo + n] = acc;
}

// -------------------------------------------------- tiled fp32 GEMM  C = A * B^T
// A[M][K] lda, B(N rows of K) ldb, C[M][N] ldc. BM=BN=128, BK=16.
// grid (N/128, M/128), block 256; each thread 8x8.
__global__ __launch_bounds__(256) void gemm_nt(
    const float* __restrict__ A, int lda,
    const float* __restrict__ Bm, int ldb,
    float* __restrict__ C, int ldc,
    int K, const float* __restrict__ bias, int act)
{
    __shared__ float As[16][128];
    __shared__ float Bs[16][128];
    const int tid = threadIdx.x;
    const int tm = tid >> 4, tn = tid & 15;
    const size_t row0 = (size_t)blockIdx.y * 128, col0 = (size_t)blockIdx.x * 128;
    float acc[8][8] = {};
    const int lr = tid >> 1;           // 0..127
    const int lc = (tid & 1) * 8;      // 0 or 8
    const float* Ap = A + (row0 + lr) * lda + lc;
    const float* Bp = Bm + (col0 + lr) * ldb + lc;
    for (int k0 = 0; k0 < K; k0 += 16) {
        float4 a0 = *(const float4*)Ap;
        float4 a1 = *(const float4*)(Ap + 4);
        float4 b0 = *(const float4*)Bp;
        float4 b1 = *(const float4*)(Bp + 4);
        Ap += 16; Bp += 16;
        As[lc + 0][lr] = a0.x; As[lc + 1][lr] = a0.y; As[lc + 2][lr] = a0.z; As[lc + 3][lr] = a0.w;
        As[lc + 4][lr] = a1.x; As[lc + 5][lr] = a1.y; As[lc + 6][lr] = a1.z; As[lc + 7][lr] = a1.w;
        Bs[lc + 0][lr] = b0.x; Bs[lc + 1][lr] = b0.y; Bs[lc + 2][lr] = b0.z; Bs[lc + 3][lr] = b0.w;
        Bs[lc + 4][lr] = b1.x; Bs[lc + 5][lr] = b1.y; Bs[lc + 6][lr] = b1.z; Bs[lc + 7][lr] = b1.w;
        __syncthreads();
#pragma unroll
        for (int k = 0; k < 16; ++k) {
            float4 av0 = *(const float4*)&As[k][tm * 8];
            float4 av1 = *(const float4*)&As[k][tm * 8 + 4];
            float4 bv0 = *(const float4*)&Bs[k][tn * 8];
            float4 bv1 = *(const float4*)&Bs[k][tn * 8 + 4];
            float am[8] = {av0.x, av0.y, av0.z, av0.w, av1.x, av1.y, av1.z, av1.w};
            float bm[8] = {bv0.x, bv0.y, bv0.z, bv0.w, bv1.x, bv1.y, bv1.z, bv1.w};
#pragma unroll
            for (int i = 0; i < 8; ++i)
#pragma unroll
                for (int jj = 0; jj < 8; ++jj)
                    acc[i][jj] += am[i] * bm[jj];
        }
        __syncthreads();
    }
#pragma unroll
    for (int i = 0; i < 8; ++i) {
        const size_t r = row0 + tm * 8 + i;
        float* cp = C + r * ldc + col0 + tn * 8;
#pragma unroll
        for (int jj = 0; jj < 8; ++jj) {
            float v = acc[i][jj];
            if (bias) v += bias[col0 + tn * 8 + jj];
            if (act)  v = tanhf(v);
            cp[jj] = v;
        }
    }
}

// -------------------------------------------------- attention (one decode step)
// grid B blocks, 256 threads: scores -> softmax -> context w -> X[.,512:1536]
__global__ __launch_bounds__(256) void attn_step(
    const float* __restrict__ enc_proj,  // [B][S][512]
    const float* __restrict__ hp,        // [B][512]
    const float* __restrict__ enc_bt,    // [B][S][1024]
    const float* __restrict__ v_attn,
    const int* __restrict__ src,         // [S][B]
    float* __restrict__ X, int t)
{
    __shared__ float hps[HD_DIM];
    __shared__ float va[HD_DIM];
    __shared__ float sc[S_LEN];
    const int b = blockIdx.x, tid = threadIdx.x;
    hps[tid] = hp[(size_t)b * HD_DIM + tid];
    hps[tid + 256] = hp[(size_t)b * HD_DIM + 256 + tid];
    va[tid] = v_attn[tid];
    va[tid + 256] = v_attn[256 + tid];
    __syncthreads();
    const int s = tid >> 2, l4 = tid & 3;
    const float* ep = enc_proj + ((size_t)b * S_LEN + s) * HD_DIM;
    float part = 0.f;
    for (int d = l4; d < HD_DIM; d += 4) part += va[d] * tanhf(ep[d] + hps[d]);
    part += __shfl_xor(part, 1);
    part += __shfl_xor(part, 2);
    if (l4 == 0) sc[s] = (src[s * BATCH + b] != 0) ? part : -1e10f;
    __syncthreads();
    if (tid < 64) {
        float x = sc[tid];
        float m = x;
        for (int o = 1; o < 64; o <<= 1) m = fmaxf(m, __shfl_xor(m, o));
        float e = expf(x - m);
        float ssum = e;
        for (int o = 1; o < 64; o <<= 1) ssum += __shfl_xor(ssum, o);
        sc[tid] = e / ssum;
    }
    __syncthreads();
    float* xw = X + ((size_t)t * BATCH + b) * XDIM + 512;
    const float* eb = enc_bt + (size_t)b * S_LEN * 1024;
#pragma unroll
    for (int c = 0; c < 4; ++c) {
        const int e = tid + 256 * c;
        float acc = 0.f;
#pragma unroll 8
        for (int s2 = 0; s2 < S_LEN; ++s2) acc += sc[s2] * eb[(size_t)s2 * 1024 + e];
        xw[e] = acc;
    }
}

// -------------------------------------------------- decoder GRU step
// grid (8 j-tiles, 16 b-tiles), block (64,8)
__global__ __launch_bounds__(512) void gru_dec_step(
    float* __restrict__ X,              // [T-1][B][1792]; reads e,w; writes h2
    const float* __restrict__ h_in,     // [B][512]
    float* __restrict__ h_out,          // [B][512]
    const float* __restrict__ Wih_d, const float* __restrict__ Whh_d,
    const float* __restrict__ bih_d, const float* __restrict__ bhh_d,
    int t)
{
    __shared__ float es[8][E_DIM];
    __shared__ float ws_[8][1024];
    __shared__ float hs[8][HD_DIM];
    const int tx = threadIdx.x, ty = threadIdx.y;
    const int tid = ty * 64 + tx;   // 0..511
    const int b0 = blockIdx.y * 8;
    const float* Xrow = X + ((size_t)t * BATCH + b0) * XDIM;
    for (int i = tid; i < 8 * E_DIM; i += 512)
        es[i >> 8][i & 255] = Xrow[(size_t)(i >> 8) * XDIM + 1536 + (i & 255)];
    for (int i = tid; i < 8 * 1024; i += 512)
        ws_[i >> 10][i & 1023] = Xrow[(size_t)(i >> 10) * XDIM + 512 + (i & 1023)];
    for (int i = tid; i < 8 * HD_DIM; i += 512)
        hs[i >> 9][i & 511] = h_in[(size_t)(b0 + (i >> 9)) * HD_DIM + (i & 511)];
    __syncthreads();
    const int j = blockIdx.x * 64 + tx;
    float g_i[3], g_h[3];
#pragma unroll
    for (int g = 0; g < 3; ++g) {
        const int row = g * HD_DIM + j;
        const float4* wi = (const float4*)(Wih_d + (size_t)row * 1280);
        const float4* ev = (const float4*)es[ty];
        float acc = bih_d[row];
#pragma unroll 4
        for (int k = 0; k < E_DIM / 4; ++k) {
            float4 w = wi[k], x = ev[k];
            acc += w.x * x.x + w.y * x.y + w.z * x.z + w.w * x.w;
        }
        const float4* wv = (const float4*)ws_[ty];
#pragma unroll 4
        for (int k = 0; k < 1024 / 4; ++k) {
            float4 w = wi[64 + k], x = wv[k];
            acc += w.x * x.x + w.y * x.y + w.z * x.z + w.w * x.w;
        }
        g_i[g] = acc;
        const float4* wh = (const float4*)(Whh_d + (size_t)row * HD_DIM);
        const float4* hv = (const float4*)hs[ty];
        acc = bhh_d[row];
#pragma unroll 4
        for (int k = 0; k < HD_DIM / 4; ++k) {
            float4 w = wh[k], h = hv[k];
            acc += w.x * h.x + w.y * h.y + w.z * h.z + w.w * h.w;
        }
        g_h[g] = acc;
    }
    float r = sigm(g_i[0] + g_h[0]);
    float z = sigm(g_i[1] + g_h[1]);
    float n = tanhf(g_i[2] + r * g_h[2]);
    float h2 = (1.f - z) * n + z * hs[ty][j];
    const int b = b0 + ty;
    h_out[(size_t)b * HD_DIM + j] = h2;
    X[((size_t)t * BATCH + b) * XDIM + j] = h2;
}

// -------------------------------------------------- in-place log-softmax per row (V=32000)
__global__ __launch_bounds__(256) void log_softmax_rows(float* __restrict__ data) {
    __shared__ float sm[256], ss[256];
    const size_t row = blockIdx.x;
    float* p = data + row * VOCAB;
    const int tid = threadIdx.x;
    float m = -3.4e38f, ssum = 0.f;
    for (int i = tid; i < VOCAB; i += 256) {
        float x = p[i];
        float mn = fmaxf(m, x);
        ssum = ssum * expf(m - mn) + expf(x - mn);
        m = mn;
    }
    sm[tid] = m; ss[tid] = ssum;
    __syncthreads();
    for (int off = 128; off > 0; off >>= 1) {
        if (tid < off) {
            float m2 = sm[tid + off], s2 = ss[tid + off];
            float M = fmaxf(sm[tid], m2);
            ss[tid] = ss[tid] * expf(sm[tid] - M) + s2 * expf(m2 - M);
            sm[tid] = M;
        }
        __syncthreads();
    }
    const float lse = sm[0] + logf(ss[0]);
    for (int i = tid; i < VOCAB; i += 256) p[i] -= lse;
}

// -------------------------------------------------- final plane t = T-1
__global__ void fill_last(float* __restrict__ out) {
    int i = blockIdx.x * 256 + threadIdx.x;
    if (i >= BATCH * VOCAB) return;
    int v = i % VOCAB;
    out[(size_t)(T_LEN - 1) * BATCH * VOCAB + i] = (v == 2) ? 100.f : 0.f;
}

// ==================================================================== launch
extern "C" void kernel_launch(void* const* d_in, const int* in_sizes, int n_in,
                              void* d_out, int out_size, void* d_ws, size_t ws_size,
                              hipStream_t stream)
{
    const int*   src     = (const int*)d_in[0];
    const int*   trg     = (const int*)d_in[2];
    const float* emb_enc = (const float*)d_in[3];
    const float* emb_dec = (const float*)d_in[4];
    const float* Wih_f   = (const float*)d_in[5];
    const float* Whh_f   = (const float*)d_in[6];
    const float* bih_f   = (const float*)d_in[7];
    const float* bhh_f   = (const float*)d_in[8];
    const float* Wih_b   = (const float*)d_in[9];
    const float* Whh_b   = (const float*)d_in[10];
    const float* bih_b   = (const float*)d_in[11];
    const float* bhh_b   = (const float*)d_in[12];
    const float* W_fc    = (const float*)d_in[13];
    const float* b_fc    = (const float*)d_in[14];
    const float* W_attn  = (const float*)d_in[15];
    const float* b_attn  = (const float*)d_in[16];
    const float* v_attn  = (const float*)d_in[17];
    const float* Wih_d   = (const float*)d_in[18];
    const float* Whh_d   = (const float*)d_in[19];
    const float* bih_d   = (const float*)d_in[20];
    const float* bhh_d   = (const float*)d_in[21];
    const float* W_out   = (const float*)d_in[22];
    const float* b_out   = (const float*)d_in[23];
    float* out = (float*)d_out;

    float* ws = (float*)d_ws;
    size_t off = 0;
    auto alloc = [&](size_t n) { float* p = ws + off; off += n; return p; };
    float* emb   = alloc((size_t)S_LEN * BATCH * E_DIM);   // 2.1M
    float* encbt = alloc((size_t)BATCH * S_LEN * 1024);    // 8.4M  [b][s][1024]
    float* encp  = alloc((size_t)BATCH * S_LEN * 512);     // 4.2M  [b][s][512]
    float* hcatA = alloc((size_t)BATCH * 1024);
    float* hcatB = alloc((size_t)BATCH * 1024);
    float* hdA   = alloc((size_t)BATCH * 512);
    float* hdB   = alloc((size_t)BATCH * 512);
    float* hp    = alloc((size_t)BATCH * 512);
    float* X     = alloc((size_t)(T_LEN - 1) * BATCH * XDIM); // 7.1M

    // embeddings + init
    gather_emb<<<(S_LEN * BATCH * E_DIM + 255) / 256, 256, 0, stream>>>(
        emb_enc, src, emb, S_LEN * BATCH * E_DIM);
    gather_trg<<<((T_LEN - 1) * BATCH * E_DIM + 255) / 256, 256, 0, stream>>>(
        emb_dec, trg, X, (T_LEN - 1) * BATCH * E_DIM);
    zero_kernel<<<(BATCH * 1024 + 255) / 256, 256, 0, stream>>>(hcatA, BATCH * 1024);

    // encoder: 64 steps, both directions per launch, ping-pong h
    for (int s = 0; s < S_LEN; ++s) {
        const float* hin  = (s & 1) ? hcatB : hcatA;
        float*       hout = (s & 1) ? hcatA : hcatB;
        gru_enc_step<<<dim3(8, 8, 2), dim3(64, 16), 0, stream>>>(
            emb, hin, hout, encbt,
            Wih_f, Whh_f, bih_f, bhh_f, Wih_b, Whh_b, bih_b, bhh_b, s);
    }
    // final h (s=63 wrote hcatA): hid = tanh([hf,hb] @ W_fc^T + b_fc)
    matvec_b<<<dim3(2, BATCH), 256, 0, stream>>>(hcatA, 1024, W_fc, 1024, hdA, 512,
                                                 1024, b_fc, 1);
    // enc_proj = enc_b @ W_a_e^T + b_attn   (M=8192, N=512, K=1024)
    gemm_nt<<<dim3(4, 64), 256, 0, stream>>>(encbt, 1024, W_attn + 512, 1536,
                                             encp, 512, 1024, b_attn, 0);
    // decoder: 31 steps
    for (int t = 0; t < T_LEN - 1; ++t) {
        const float* hin  = (t & 1) ? hdB : hdA;
        float*       hout = (t & 1) ? hdA : hdB;
        matvec_b<<<dim3(2, BATCH), 256, 0, stream>>>(hin, 512, W_attn, 1536, hp, 512,
                                                     512, nullptr, 0);
        attn_step<<<BATCH, 256, 0, stream>>>(encp, hp, encbt, v_attn, src, X, t);
        gru_dec_step<<<dim3(8, 16), dim3(64, 8), 0, stream>>>(
            X, hin, hout, Wih_d, Whh_d, bih_d, bhh_d, t);
    }
    // logits for all 31 steps in one GEMM: (3968 x 32000, K=1792) -> d_out
    gemm_nt<<<dim3(VOCAB / 128, (T_LEN - 1) * BATCH / 128), 256, 0, stream>>>(
        X, XDIM, W_out, XDIM, out, VOCAB, XDIM, b_out, 0);
    // in-place log-softmax on the 3968 rows
    log_softmax_rows<<<(T_LEN - 1) * BATCH, 256, 0, stream>>>(out);
    // last plane: zeros with 100 at EOS
    fill_last<<<(BATCH * VOCAB + 255) / 256, 256, 0, stream>>>(out);
}

// Round 2
// 5428.259 us; speedup vs baseline: 6.2826x; 6.2826x over previous
//
#include <hip/hip_runtime.h>
#include <cstddef>
#include <cstdint>

#define S_LEN 64
#define BATCH 128
#define T_LEN 32
#define E_DIM 256
#define HE 512
#define HD 512
#define VOCAB 32000
#define XDIM 1792   // HD + 2*HE + E

typedef unsigned short bfu;
typedef short short8 __attribute__((ext_vector_type(8)));
typedef float f32x4 __attribute__((ext_vector_type(4)));

__device__ __forceinline__ float sigm(float x) { return 1.f / (1.f + expf(-x)); }
__device__ __forceinline__ bfu f2b(float f) {
    unsigned int x = __float_as_uint(f);
    x += 0x7fffu + ((x >> 16) & 1u);
    return (bfu)(x >> 16);
}
__device__ __forceinline__ float b2f(bfu u) {
    return __uint_as_float(((unsigned int)u) << 16);
}

// ---------------------------------------------------------------- utilities
__global__ void zero_kernel(float* __restrict__ p, int n) {
    int i = blockIdx.x * 256 + threadIdx.x;
    if (i < n) p[i] = 0.f;
}

__global__ void conv_f2b(const float* __restrict__ in, bfu* __restrict__ out, int n4) {
    int i = blockIdx.x * 256 + threadIdx.x;
    if (i >= n4) return;
    float4 v = ((const float4*)in)[i];
    ushort4 o;
    o.x = f2b(v.x); o.y = f2b(v.y); o.z = f2b(v.z); o.w = f2b(v.w);
    ((ushort4*)out)[i] = o;
}

// out[row][k] = bf16(table[idx[row]*E + k]); row-major [rows][E_DIM]
__global__ void gather_emb(const float* __restrict__ table, const int* __restrict__ idx,
                           bfu* __restrict__ out, int total) {
    int i = blockIdx.x * 256 + threadIdx.x;
    if (i >= total) return;
    int row = i >> 8;
    int k   = i & 255;
    out[i] = f2b(table[(size_t)idx[row] * E_DIM + k]);
}

// Xb[row][1536+k] = bf16(emb_dec[trg[row]*E + k]), row = t*B+b, t<T-1
__global__ void gather_trg(const float* __restrict__ table, const int* __restrict__ trg,
                           bfu* __restrict__ Xb, int total) {
    int i = blockIdx.x * 256 + threadIdx.x;
    if (i >= total) return;
    int row = i >> 8;
    int k   = i & 255;
    Xb[(size_t)row * XDIM + 1536 + k] = f2b(table[(size_t)trg[row] * E_DIM + k]);
}

// ----------------------------------------------- generic bf16 MFMA GEMM (NT)
// C[M][N] = A[M][K](bf16) * W[N][K](bf16)^T + bias; optional tanh; optional
// bf16 mirror Cb (z==0 only). Two parameter sets selected by blockIdx.z.
// Tiles: BM=BN=128, BK=32; 256 threads = 4 waves (2x2), wave tile 64x64.
// LDS per tile: [kc=4][row=128][8] bf16 (conflict-free frag reads); staged
// via global_load_lds width 16 (linear dest, chunk c -> kc=c>>7, r=c&127).
#define GLDS(gsrc, ldst)                                                          \
    __builtin_amdgcn_global_load_lds(                                             \
        (const __attribute__((address_space(1))) void*)(gsrc),                    \
        (__attribute__((address_space(3))) void*)(ldst), 16, 0, 0)

__global__ __launch_bounds__(256) void gemm_bf16(
    const bfu* __restrict__ A0, int lda0, const bfu* __restrict__ W0, int ldw0,
    float* __restrict__ C0, int ldc0, const float* __restrict__ bias0, int K0,
    const bfu* __restrict__ A1, int lda1, const bfu* __restrict__ W1, int ldw1,
    float* __restrict__ C1, int ldc1, const float* __restrict__ bias1, int K1,
    int act, bfu* __restrict__ Cb0)
{
    const int z = blockIdx.z;
    const bfu* A = z ? A1 : A0;
    const bfu* W = z ? W1 : W0;
    float*     C = z ? C1 : C0;
    const float* bias = z ? bias1 : bias0;
    bfu*       Cb = z ? nullptr : Cb0;
    const int lda = z ? lda1 : lda0;
    const int ldw = z ? ldw1 : ldw0;
    const int ldc = z ? ldc1 : ldc0;
    const int K   = z ? K1 : K0;

    __shared__ short lds[2][2][4096];   // [buf][A/B][kc*1024 + row*8 + i]
    const int tid  = threadIdx.x;
    const int wid  = tid >> 6, lane = tid & 63;
    const int l15  = lane & 15, lk = lane >> 4;
    const int wr   = (wid >> 1) * 64, wc = (wid & 1) * 64;
    const size_t row0 = (size_t)blockIdx.y * 128;
    const size_t col0 = (size_t)blockIdx.x * 128;

    const int c0 = tid, c1 = tid + 256;
    const int r0 = c0 & 127, kc0 = c0 >> 7;
    const int r1 = c1 & 127, kc1 = c1 >> 7;
    const int sb0 = (wid * 64) * 16;          // wave-uniform LDS byte offsets
    const int sb1 = (wid * 64 + 256) * 16;

    f32x4 acc[4][4];
#pragma unroll
    for (int m = 0; m < 4; ++m)
#pragma unroll
        for (int n = 0; n < 4; ++n) acc[m][n] = (f32x4){0.f, 0.f, 0.f, 0.f};

    auto stage = [&](int buf, int kt) {
        char* ba = (char*)&lds[buf][0][0];
        char* bb = (char*)&lds[buf][1][0];
        GLDS(A + (row0 + r0) * (size_t)lda + kt + kc0 * 8, ba + sb0);
        GLDS(A + (row0 + r1) * (size_t)lda + kt + kc1 * 8, ba + sb1);
        GLDS(W + (col0 + r0) * (size_t)ldw + kt + kc0 * 8, bb + sb0);
        GLDS(W + (col0 + r1) * (size_t)ldw + kt + kc1 * 8, bb + sb1);
    };

    stage(0, 0);
    __syncthreads();
    const int nk = K >> 5;
    for (int t = 0; t < nk; ++t) {
        const int buf = t & 1;
        if (t + 1 < nk) stage(buf ^ 1, (t + 1) << 5);
        short8 af[4], bf_[4];
#pragma unroll
        for (int m = 0; m < 4; ++m)
            af[m] = *(const short8*)&lds[buf][0][lk * 1024 + (wr + m * 16 + l15) * 8];
#pragma unroll
        for (int n = 0; n < 4; ++n)
            bf_[n] = *(const short8*)&lds[buf][1][lk * 1024 + (wc + n * 16 + l15) * 8];
#pragma unroll
        for (int m = 0; m < 4; ++m)
#pragma unroll
            for (int n = 0; n < 4; ++n)
                acc[m][n] = __builtin_amdgcn_mfma_f32_16x16x32_bf16(
                    af[m], bf_[n], acc[m][n], 0, 0, 0);
        __syncthreads();
    }

    float bv[4];
#pragma unroll
    for (int n = 0; n < 4; ++n)
        bv[n] = bias ? bias[col0 + wc + n * 16 + l15] : 0.f;
    const size_t crow = row0 + wr + lk * 4;
#pragma unroll
    for (int m = 0; m < 4; ++m) {
#pragma unroll
        for (int q = 0; q < 4; ++q) {
            const size_t r = crow + m * 16 + q;
            float* cp = C + r * ldc + col0 + wc + l15;
            bfu*   cb = Cb ? (Cb + r * ldc + col0 + wc + l15) : nullptr;
#pragma unroll
            for (int n = 0; n < 4; ++n) {
                float v = acc[m][n][q] + bv[n];
                if (act) v = tanhf(v);
                cp[n * 16] = v;
                if (Cb) cb[n * 16] = f2b(v);
            }
        }
    }
}

// ----------------------------------------------- encoder gate (elementwise)
// i over 2*512*128: b = i>>10, dir = (i>>9)&1, u = i&511
__global__ __launch_bounds__(256) void gate_enc(
    const float* __restrict__ gi_f, const float* __restrict__ gi_b,
    const float* __restrict__ gh_f, const float* __restrict__ gh_b,
    const float* __restrict__ hin, float* __restrict__ hout,
    bfu* __restrict__ hbout, bfu* __restrict__ encbt, int s)
{
    int i = blockIdx.x * 256 + threadIdx.x;
    int b = i >> 10, rest = i & 1023, dir = rest >> 9, u = rest & 511;
    int p = dir ? (S_LEN - 1 - s) : s;
    const float* gi = (dir ? gi_b : gi_f) + ((size_t)p * BATCH + b) * 1536;
    const float* gh = (dir ? gh_b : gh_f) + (size_t)b * 1536;
    float r = sigm(gi[u] + gh[u]);
    float zz = sigm(gi[512 + u] + gh[512 + u]);
    float n = tanhf(gi[1024 + u] + r * gh[1024 + u]);
    float hp = hin[(size_t)b * 1024 + dir * 512 + u];
    float h2 = (1.f - zz) * n + zz * hp;
    hout[(size_t)b * 1024 + dir * 512 + u] = h2;
    hbout[(size_t)b * 1024 + dir * 512 + u] = f2b(h2);
    encbt[((size_t)b * S_LEN + p) * 1024 + dir * 512 + u] = f2b(h2);
}

// ----------------------------------------------- decoder gate (elementwise)
__global__ __launch_bounds__(256) void gate_dec(
    const float* __restrict__ gie, const float* __restrict__ giw,
    const float* __restrict__ gh, const float* __restrict__ hin,
    float* __restrict__ hout, bfu* __restrict__ hbout,
    bfu* __restrict__ Xb, int t)
{
    int i = blockIdx.x * 256 + threadIdx.x;     // 65536
    int b = i >> 9, u = i & 511;
    const float* ge = gie + ((size_t)t * BATCH + b) * 1536;
    const float* gw = giw + (size_t)b * 1536;
    const float* gH = gh + (size_t)b * 1536;
    float r = sigm(ge[u] + gw[u] + gH[u]);
    float zz = sigm(ge[512 + u] + gw[512 + u] + gH[512 + u]);
    float n = tanhf(ge[1024 + u] + gw[1024 + u] + r * gH[1024 + u]);
    float h2 = (1.f - zz) * n + zz * hin[i];
    hout[i] = h2;
    hbout[i] = f2b(h2);
    Xb[((size_t)t * BATCH + b) * XDIM + u] = f2b(h2);
}

// ----------------------------------------------- fused hp + attention step
__global__ __launch_bounds__(256) void attn_fused(
    const bfu* __restrict__ hb,          // [B][512] decoder h (bf16)
    const bfu* __restrict__ Wahb,        // W_attn bf16, rows*1536, cols 0..511
    const float* __restrict__ encp,      // [B*S][512]
    const bfu* __restrict__ encbt,       // [B*S][1024]
    const float* __restrict__ v_attn, const int* __restrict__ src,
    bfu* __restrict__ Xb, int t)
{
    __shared__ float hls[512];
    __shared__ float vas[512];
    __shared__ float hps[512];
    __shared__ float sc[64];
    const int b = blockIdx.x, tid = threadIdx.x;
    for (int i = tid; i < 512; i += 256) {
        hls[i] = b2f(hb[(size_t)b * 512 + i]);
        vas[i] = v_attn[i];
    }
    __syncthreads();
    // hp[j] = dot(h, W_a_h[j])
    for (int j = tid; j < 512; j += 256) {
        const uint4* wrow = (const uint4*)(Wahb + (size_t)j * 1536);
        float acc = 0.f;
#pragma unroll 8
        for (int k8 = 0; k8 < 64; ++k8) {
            uint4 wv = wrow[k8];
            const float* xp = &hls[k8 * 8];
            acc += __uint_as_float(wv.x << 16) * xp[0] + __uint_as_float(wv.x & 0xffff0000u) * xp[1]
                 + __uint_as_float(wv.y << 16) * xp[2] + __uint_as_float(wv.y & 0xffff0000u) * xp[3]
                 + __uint_as_float(wv.z << 16) * xp[4] + __uint_as_float(wv.z & 0xffff0000u) * xp[5]
                 + __uint_as_float(wv.w << 16) * xp[6] + __uint_as_float(wv.w & 0xffff0000u) * xp[7];
        }
        hps[j] = acc;
    }
    __syncthreads();
    // scores
    const int s = tid >> 2, l4 = tid & 3;
    const float* ep = encp + ((size_t)b * S_LEN + s) * 512;
    float part = 0.f;
#pragma unroll 4
    for (int d = l4; d < 512; d += 4) part += vas[d] * tanhf(ep[d] + hps[d]);
    part += __shfl_xor(part, 1);
    part += __shfl_xor(part, 2);
    if (l4 == 0) sc[s] = (src[s * BATCH + b] != 0) ? part : -1e10f;
    __syncthreads();
    if (tid < 64) {
        float x = sc[tid], m = x;
        for (int o = 1; o < 64; o <<= 1) m = fmaxf(m, __shfl_xor(m, o));
        float e = expf(x - m), ss = e;
        for (int o = 1; o < 64; o <<= 1) ss += __shfl_xor(ss, o);
        sc[tid] = e / ss;
    }
    __syncthreads();
    // context -> Xb w-section (bf16)
    bfu* xw = Xb + ((size_t)t * BATCH + b) * XDIM + 512;
    const bfu* eb = encbt + (size_t)b * S_LEN * 1024;
#pragma unroll
    for (int c = 0; c < 4; ++c) {
        int e = tid + 256 * c;
        float acc = 0.f;
#pragma unroll 8
        for (int s2 = 0; s2 < S_LEN; ++s2) acc += sc[s2] * b2f(eb[(size_t)s2 * 1024 + e]);
        xw[e] = f2b(acc);
    }
}

// ------------------------------------------- in-place log-softmax (V=32000)
__global__ __launch_bounds__(256) void log_softmax_rows(float* __restrict__ data) {
    __shared__ float sm[256], ss[256];
    const size_t row = blockIdx.x;
    float* p = data + row * VOCAB;
    const int tid = threadIdx.x;
    float m = -3.4e38f, ssum = 0.f;
    for (int i = tid; i < VOCAB; i += 256) {
        float x = p[i];
        float mn = fmaxf(m, x);
        ssum = ssum * expf(m - mn) + expf(x - mn);
        m = mn;
    }
    sm[tid] = m; ss[tid] = ssum;
    __syncthreads();
    for (int off = 128; off > 0; off >>= 1) {
        if (tid < off) {
            float m2 = sm[tid + off], s2 = ss[tid + off];
            float M = fmaxf(sm[tid], m2);
            ss[tid] = ss[tid] * expf(sm[tid] - M) + s2 * expf(m2 - M);
            sm[tid] = M;
        }
        __syncthreads();
    }
    const float lse = sm[0] + logf(ss[0]);
    for (int i = tid; i < VOCAB; i += 256) p[i] -= lse;
}

__global__ void fill_last(float* __restrict__ out) {
    int i = blockIdx.x * 256 + threadIdx.x;
    if (i >= BATCH * VOCAB) return;
    int v = i % VOCAB;
    out[(size_t)(T_LEN - 1) * BATCH * VOCAB + i] = (v == 2) ? 100.f : 0.f;
}

// ==================================================================== launch
extern "C" void kernel_launch(void* const* d_in, const int* in_sizes, int n_in,
                              void* d_out, int out_size, void* d_ws, size_t ws_size,
                              hipStream_t stream)
{
    const int*   src     = (const int*)d_in[0];
    const int*   trg     = (const int*)d_in[2];
    const float* emb_enc = (const float*)d_in[3];
    const float* emb_dec = (const float*)d_in[4];
    const float* Wih_f   = (const float*)d_in[5];
    const float* Whh_f   = (const float*)d_in[6];
    const float* bih_f   = (const float*)d_in[7];
    const float* bhh_f   = (const float*)d_in[8];
    const float* Wih_b   = (const float*)d_in[9];
    const float* Whh_b   = (const float*)d_in[10];
    const float* bih_b   = (const float*)d_in[11];
    const float* bhh_b   = (const float*)d_in[12];
    const float* W_fc    = (const float*)d_in[13];
    const float* b_fc    = (const float*)d_in[14];
    const float* W_attn  = (const float*)d_in[15];
    const float* b_attn  = (const float*)d_in[16];
    const float* v_attn  = (const float*)d_in[17];
    const float* Wih_d   = (const float*)d_in[18];
    const float* Whh_d   = (const float*)d_in[19];
    const float* bih_d   = (const float*)d_in[20];
    const float* bhh_d   = (const float*)d_in[21];
    const float* W_out   = (const float*)d_in[22];
    const float* b_out   = (const float*)d_in[23];
    float* out = (float*)d_out;

    char* wsb = (char*)d_ws;
    size_t off = 0;
    auto alloc = [&](size_t bytes) { void* q = wsb + off; off = (off + bytes + 255) & ~(size_t)255; return q; };
    bfu*   emb_b   = (bfu*)alloc((size_t)8192 * 256 * 2);
    bfu*   encbt_b = (bfu*)alloc((size_t)8192 * 1024 * 2);
    float* encp    = (float*)alloc((size_t)8192 * 512 * 4);
    float* gi_f    = (float*)alloc((size_t)8192 * 1536 * 4);
    float* gi_b    = (float*)alloc((size_t)8192 * 1536 * 4);
    float* gie     = (float*)alloc((size_t)3968 * 1536 * 4);
    float* giw     = (float*)alloc((size_t)128 * 1536 * 4);
    float* ghd     = (float*)alloc((size_t)128 * 1536 * 4);
    float* ghf     = (float*)alloc((size_t)128 * 1536 * 4);
    float* ghb     = (float*)alloc((size_t)128 * 1536 * 4);
    float* hA      = (float*)alloc((size_t)128 * 1024 * 4);
    float* hB      = (float*)alloc((size_t)128 * 1024 * 4);
    bfu*   hbA     = (bfu*)alloc((size_t)128 * 1024 * 2);
    bfu*   hbB     = (bfu*)alloc((size_t)128 * 1024 * 2);
    float* hdA     = (float*)alloc((size_t)128 * 512 * 4);
    float* hdB     = (float*)alloc((size_t)128 * 512 * 4);
    bfu*   hdbA    = (bfu*)alloc((size_t)128 * 512 * 2);
    bfu*   hdbB    = (bfu*)alloc((size_t)128 * 512 * 2);
    bfu*   Xb      = (bfu*)alloc((size_t)3968 * XDIM * 2);
    bfu*   Wihf_b  = (bfu*)alloc((size_t)1536 * 256 * 2);
    bfu*   Wihb_b  = (bfu*)alloc((size_t)1536 * 256 * 2);
    bfu*   Whhf_b  = (bfu*)alloc((size_t)1536 * 512 * 2);
    bfu*   Whhb_b  = (bfu*)alloc((size_t)1536 * 512 * 2);
    bfu*   Wfc_b   = (bfu*)alloc((size_t)512 * 1024 * 2);
    bfu*   Wattn_b = (bfu*)alloc((size_t)512 * 1536 * 2);
    bfu*   Wihd_b  = (bfu*)alloc((size_t)1536 * 1280 * 2);
    bfu*   Whhd_b  = (bfu*)alloc((size_t)1536 * 512 * 2);
    bfu*   Wout_b  = (bfu*)alloc((size_t)VOCAB * XDIM * 2);

    auto conv = [&](const float* in, bfu* o, size_t n) {
        conv_f2b<<<(int)((n / 4 + 255) / 256), 256, 0, stream>>>(in, o, (int)(n / 4));
    };
    conv(Wih_f, Wihf_b, 1536 * 256);
    conv(Wih_b, Wihb_b, 1536 * 256);
    conv(Whh_f, Whhf_b, 1536 * 512);
    conv(Whh_b, Whhb_b, 1536 * 512);
    conv(W_fc,  Wfc_b,  512 * 1024);
    conv(W_attn, Wattn_b, 512 * 1536);
    conv(Wih_d, Wihd_b, 1536 * 1280);
    conv(Whh_d, Whhd_b, 1536 * 512);
    conv(W_out, Wout_b, (size_t)VOCAB * XDIM);

    gather_emb<<<(8192 * 256 + 255) / 256, 256, 0, stream>>>(emb_enc, src, emb_b, 8192 * 256);
    gather_trg<<<(3968 * 256 + 255) / 256, 256, 0, stream>>>(emb_dec, trg, Xb, 3968 * 256);
    zero_kernel<<<(131072 + 255) / 256, 256, 0, stream>>>(hA, 131072);
    zero_kernel<<<(65536 + 255) / 256, 256, 0, stream>>>((float*)hbA, 65536);

    // gi for all encoder steps, both dirs:  [8192][1536] = emb @ Wih^T + bih
    gemm_bf16<<<dim3(12, 64, 2), 256, 0, stream>>>(
        emb_b, 256, Wihf_b, 256, gi_f, 1536, bih_f, 256,
        emb_b, 256, Wihb_b, 256, gi_b, 1536, bih_b, 256, 0, nullptr);

    // gi_e for all decoder steps: [3968][1536] = e @ Wih_d[:, :256]^T + bih_d
    gemm_bf16<<<dim3(12, 31, 1), 256, 0, stream>>>(
        Xb + 1536, XDIM, Wihd_b, 1280, gie, 1536, bih_d, 256,
        Xb + 1536, XDIM, Wihd_b, 1280, gie, 1536, bih_d, 256, 0, nullptr);

    // encoder recurrence
    for (int s = 0; s < S_LEN; ++s) {
        const float* hin  = (s & 1) ? hB : hA;
        float*       hout = (s & 1) ? hA : hB;
        const bfu*   hbin = (s & 1) ? hbB : hbA;
        bfu*         hbout = (s & 1) ? hbA : hbB;
        gemm_bf16<<<dim3(12, 1, 2), 256, 0, stream>>>(
            hbin, 1024, Whhf_b, 512, ghf, 1536, bhh_f, 512,
            hbin + 512, 1024, Whhb_b, 512, ghb, 1536, bhh_b, 512, 0, nullptr);
        gate_enc<<<131072 / 256, 256, 0, stream>>>(
            gi_f, gi_b, ghf, ghb, hin, hout, hbout, encbt_b, s);
    }
    // hid = tanh([hf,hb] @ W_fc^T + b_fc)  (final enc h lives in hA/hbA)
    gemm_bf16<<<dim3(4, 1, 1), 256, 0, stream>>>(
        hbA, 1024, Wfc_b, 1024, hdA, 512, b_fc, 1024,
        hbA, 1024, Wfc_b, 1024, hdA, 512, b_fc, 1024, 1, hdbA);
    // enc_proj = enc_bt @ W_a_e^T + b_attn   [8192][512]
    gemm_bf16<<<dim3(4, 64, 1), 256, 0, stream>>>(
        encbt_b, 1024, Wattn_b + 512, 1536, encp, 512, b_attn, 1024,
        encbt_b, 1024, Wattn_b + 512, 1536, encp, 512, b_attn, 1024, 0, nullptr);

    // decoder recurrence
    for (int t = 0; t < T_LEN - 1; ++t) {
        const float* hin  = (t & 1) ? hdB : hdA;
        float*       hout = (t & 1) ? hdA : hdB;
        const bfu*   hbin = (t & 1) ? hdbB : hdbA;
        bfu*         hbout = (t & 1) ? hdbA : hdbB;
        attn_fused<<<BATCH, 256, 0, stream>>>(hbin, Wattn_b, encp, encbt_b,
                                              v_attn, src, Xb, t);
        gemm_bf16<<<dim3(12, 1, 2), 256, 0, stream>>>(
            Xb + (size_t)t * BATCH * XDIM + 512, XDIM, Wihd_b + 256, 1280, giw, 1536, nullptr, 1024,
            hbin, 512, Whhd_b, 512, ghd, 1536, bhh_d, 512, 0, nullptr);
        gate_dec<<<65536 / 256, 256, 0, stream>>>(gie, giw, ghd, hin, hout, hbout, Xb, t);
    }

    // logits: [3968][32000] = Xb @ W_out^T + b_out
    gemm_bf16<<<dim3(VOCAB / 128, 31, 1), 256, 0, stream>>>(
        Xb, XDIM, Wout_b, XDIM, out, VOCAB, b_out, XDIM,
        Xb, XDIM, Wout_b, XDIM, out, VOCAB, b_out, XDIM, 0, nullptr);
    log_softmax_rows<<<3968, 256, 0, stream>>>(out);
    fill_last<<<(BATCH * VOCAB + 255) / 256, 256, 0, stream>>>(out);
}